// Round 8
// baseline (64.532 us; speedup 1.0000x reference)
//
#include <hip/hip_runtime.h>
#include <math.h>

// PeakSense: out[b,p] = sum_i exp(-0.5*(mz[b,i]-mu[p])^2 * exp(-lv[p])) * iv[b,i],
// terms with arg < -10 dropped.
//
// R8 = R7 (64.1us) + one more overlap doubling, fetch-neutral:
//  - 4 blocks/CU (1024 blocks of 256 threads = 16 waves/CU in 4 independent
//    barrier groups): staging-wait / LDS-search / main-loop phases of
//    different blocks interleave on the SIMDs (m114 co-scheduling).
//    R7 had 2 groups; gain was -0.8us, so this is the last doubling that
//    can pay (LDS caps at 4x32KB=128KB of 160KB).
//  - fetch stays ~4.5MB: grid(B, pgroups=8) gives row b's 8 blocks linear
//    ids b+128k, all == b mod 8 -> same XCD -> 1 cold HBM fetch + 7 L2
//    hits. Redundant re-staging through L2 is ~32MB @ 34TB/s ~ 1us total.
//  - SUB=8, 32 peaks/block, ~9 main-loop terms per lane.
// Structure otherwise identical: float4 issue-early staging, lane-
// contiguous ds_write_b128, one barrier, split LDS binary search (even
// subs lower bound, odd subs upper, 12 uniform steps), shfl merge, exact
// per-term threshold test -> same accumulation set as ref.

#define BLOCK 256
#define SUB 8
#define PPB (BLOCK / SUB)   // 32 peaks per block
#define MAXL 4096
#define THRESH -10.0f

__global__ __launch_bounds__(BLOCK) void peaksense_kernel(
    const float* __restrict__ mu,
    const float* __restrict__ lv,
    const float* __restrict__ masses,
    const float* __restrict__ inten,
    float* __restrict__ out,
    int B, int L, int N)
{
    __shared__ float sm[MAXL];   // masses, 16 KB
    __shared__ float si[MAXL];   // intensities, 16 KB

    const int b  = blockIdx.x;   // row (fast dispatch axis)
    const int pg = blockIdx.y;   // peak group (slow axis -> same-XCD sets)
    const int t  = threadIdx.x;

    // ---- hoisted peak-parameter loads ----
    const int  lp     = t >> 3;        // local peak 0..31
    const int  sub    = t & 7;         // eighth-range selector
    const int  p      = pg * PPB + lp;
    const bool active = (p < N);
    const int  pc     = active ? p : (N - 1);   // clamp for safe loads
    const float mu_p  = mu[pc];                 // 8 lanes broadcast-share
    const float lvp   = lv[pc];

    const float* __restrict__ mrow = masses + (size_t)b * L;
    const float* __restrict__ irow = inten  + (size_t)b * L;

    const bool fast = (L == MAXL);   // L=4096: statically unrolled staging

    // ---- stage the whole row: issue all loads first, write LDS after ----
    if (fast) {
        const float4* __restrict__ m4 = reinterpret_cast<const float4*>(mrow);
        const float4* __restrict__ i4 = reinterpret_cast<const float4*>(irow);
        float4 mv[4], iv[4];
        #pragma unroll
        for (int k = 0; k < 4; ++k) mv[k] = m4[t + k * BLOCK];
        #pragma unroll
        for (int k = 0; k < 4; ++k) iv[k] = i4[t + k * BLOCK];
        float4* __restrict__ smw = reinterpret_cast<float4*>(sm);
        float4* __restrict__ siw = reinterpret_cast<float4*>(si);
        #pragma unroll
        for (int k = 0; k < 4; ++k) smw[t + k * BLOCK] = mv[k];
        #pragma unroll
        for (int k = 0; k < 4; ++k) siw[t + k * BLOCK] = iv[k];
    } else {
        for (int i = t; i < L; i += BLOCK) {
            sm[i] = mrow[i];
            si[i] = irow[i];
        }
    }

    const float inv  = __expf(-lvp);           // 1/sigma^2
    const float nh   = -0.5f * inv;
    // arg >= -10  <=>  |d| <= sqrt(20)*sigma; margin covers fp rounding, the
    // exact per-term test below keeps the result bit-for-bit identical.
    const float r    = sqrtf(20.0f / inv) * 1.00001f + 1e-3f;
    const float tlo  = mu_p - r;
    const float thi  = mu_p + r;

    __syncthreads();               // only barrier; no thread returned above

    // ---- split binary search in LDS (no HBM reads at all):
    // even subs: first i with m >= tlo; odd subs: first i with m > thi.
    // 12 uniform iterations for L=4096 -> no trip-count divergence;
    // within an 8-lane group mids coincide 4-wise -> LDS broadcast.
    const bool  isHi   = sub & 1;
    const float target = isHi ? thi : tlo;
    int lo = 0, hi = L;
    while (lo < hi) {
        const int   mid = (lo + hi) >> 1;
        const float v   = sm[mid];
        const bool  go  = isHi ? (v <= target) : (v < target);
        if (go) lo = mid + 1; else hi = mid;
    }
    const int other = __shfl_xor(lo, 1);
    const int start = isHi ? other : lo;
    const int end   = isHi ? lo    : other;

    // ---- main loop: ~9 terms per lane from LDS ----
    float acc = 0.0f;
    for (int i = start + sub; i < end; i += SUB) {
        const float d   = sm[i] - mu_p;
        const float arg = d * d * nh;
        if (arg >= THRESH)
            acc += __expf(arg) * si[i];
    }
    acc += __shfl_xor(acc, 1);                 // merge the 8-lane group
    acc += __shfl_xor(acc, 2);
    acc += __shfl_xor(acc, 4);
    if (sub == 0 && active)
        out[(size_t)b * N + p] = acc;          // exactly-once '=' write
}

extern "C" void kernel_launch(void* const* d_in, const int* in_sizes, int n_in,
                              void* d_out, int out_size, void* d_ws, size_t ws_size,
                              hipStream_t stream) {
    const float* mu     = (const float*)d_in[0];
    const float* lv     = (const float*)d_in[1];
    const float* masses = (const float*)d_in[2];
    const float* inten  = (const float*)d_in[3];
    float* out = (float*)d_out;

    const int N = in_sizes[0];
    const int B = out_size / N;
    const int L = in_sizes[2] / B;

    const int pgroups = (N + PPB - 1) / PPB;   // 8 for N=256
    dim3 grid(B, pgroups);                     // row fast -> same-XCD sets
    peaksense_kernel<<<grid, BLOCK, 0, stream>>>(mu, lv, masses, inten, out, B, L, N);
}